// Round 6
// baseline (385.316 us; speedup 1.0000x reference)
//
#include <hip/hip_runtime.h>

#define N_NODES 50000
#define N_EDGES 800000
#define CH 128
#define NOUT 10
#define NUM_GRAPHS 128
#define SCAN_B 256
#define N_SCAN_BLOCKS ((N_NODES + SCAN_B - 1) / SCAN_B)   // 196
#define POOL_CHUNK 50
#define GR 64   // gemm rows per block

// ---------- CSR build ----------
__global__ void k_hist(const int* __restrict__ dst, int* __restrict__ cnt) {
    int e = blockIdx.x * blockDim.x + threadIdx.x;
    if (e < N_EDGES) atomicAdd(&cnt[dst[e]], 1);
}

__global__ __launch_bounds__(SCAN_B) void k_scan1(const int* __restrict__ cnt,
                                                  int* __restrict__ row_start,
                                                  int* __restrict__ bsum) {
    __shared__ int s[SCAN_B];
    int tid = threadIdx.x;
    int i = blockIdx.x * SCAN_B + tid;
    int v = (i < N_NODES) ? cnt[i] : 0;
    s[tid] = v;
    __syncthreads();
    for (int off = 1; off < SCAN_B; off <<= 1) {
        int t = (tid >= off) ? s[tid - off] : 0;
        __syncthreads();
        s[tid] += t;
        __syncthreads();
    }
    if (i < N_NODES) row_start[i] = s[tid] - v;
    if (tid == SCAN_B - 1) bsum[blockIdx.x] = s[tid];
}

__global__ __launch_bounds__(SCAN_B) void k_scan2(int* __restrict__ bsum) {
    __shared__ int s[SCAN_B];
    int tid = threadIdx.x;
    int v = (tid < N_SCAN_BLOCKS) ? bsum[tid] : 0;
    s[tid] = v;
    __syncthreads();
    for (int off = 1; off < SCAN_B; off <<= 1) {
        int t = (tid >= off) ? s[tid - off] : 0;
        __syncthreads();
        s[tid] += t;
        __syncthreads();
    }
    if (tid < N_SCAN_BLOCKS) bsum[tid] = s[tid] - v;
}

__global__ __launch_bounds__(SCAN_B) void k_scan3(int* __restrict__ row_start,
                                                  const int* __restrict__ bsum,
                                                  int* __restrict__ fill_pos,
                                                  const int* __restrict__ cnt,
                                                  float* __restrict__ dinv) {
    int i = blockIdx.x * SCAN_B + threadIdx.x;
    if (i < N_NODES) {
        int rs = row_start[i] + bsum[blockIdx.x];
        row_start[i] = rs;
        fill_pos[i] = rs;
        dinv[i] = rsqrtf((float)(cnt[i] + 1));
    }
}

// fill (src, dinv[src]) pairs
__global__ void k_fill(const int* __restrict__ src, const int* __restrict__ dst,
                       int* __restrict__ fill_pos, const float* __restrict__ dinv,
                       int2* __restrict__ csr_uw) {
    int e = blockIdx.x * blockDim.x + threadIdx.x;
    if (e < N_EDGES) {
        int u = src[e];
        int pos = atomicAdd(&fill_pos[dst[e]], 1);
        csr_uw[pos] = make_int2(u, __float_as_int(dinv[u]));
    }
}

// ---------- register-tiled GEMM v3: Y[N,128] = X[N,128] @ W[128,128] ----------
// 64 rows x 128 cols per block; 256 threads = 8 groups x 32 lanes.
// k-loop in float4 chunks: per 4 k-steps -> 8 ds_read_b128 + 4 W float4 loads
// + 128 FMAs (4x fewer LDS instructions than scalar-k version).
__global__ __launch_bounds__(256) void k_gemm3(const float* __restrict__ X,
                                               const float* __restrict__ W,
                                               float* __restrict__ Y) {
    __shared__ float xs[GR][CH];
    const int tid = threadIdx.x;
    const int lane = tid & 31;
    const int g = tid >> 5;
    const int row0 = blockIdx.x * GR;

    const float4* Xv = (const float4*)X;
    #pragma unroll
    for (int i = 0; i < 8; ++i) {
        int f = tid + i * 256;
        int r = f >> 5;
        float4 val = make_float4(0.f, 0.f, 0.f, 0.f);
        if (row0 + r < N_NODES) val = Xv[(size_t)row0 * 32 + f];
        ((float4*)xs)[f] = val;
    }
    __syncthreads();

    float4 acc[8];
    #pragma unroll
    for (int i = 0; i < 8; ++i) acc[i] = make_float4(0.f, 0.f, 0.f, 0.f);

    const float4* Wv = (const float4*)W;
    #pragma unroll 2
    for (int k4 = 0; k4 < CH / 4; ++k4) {
        float4 w0 = Wv[(k4 * 4 + 0) * 32 + lane];
        float4 w1 = Wv[(k4 * 4 + 1) * 32 + lane];
        float4 w2 = Wv[(k4 * 4 + 2) * 32 + lane];
        float4 w3 = Wv[(k4 * 4 + 3) * 32 + lane];
        float4 xr[8];
        #pragma unroll
        for (int i = 0; i < 8; ++i)
            xr[i] = *(const float4*)&xs[g * 8 + i][k4 * 4];   // ds_read_b128
        #pragma unroll
        for (int i = 0; i < 8; ++i) {
            acc[i].x = fmaf(xr[i].x, w0.x, acc[i].x);
            acc[i].y = fmaf(xr[i].x, w0.y, acc[i].y);
            acc[i].z = fmaf(xr[i].x, w0.z, acc[i].z);
            acc[i].w = fmaf(xr[i].x, w0.w, acc[i].w);
            acc[i].x = fmaf(xr[i].y, w1.x, acc[i].x);
            acc[i].y = fmaf(xr[i].y, w1.y, acc[i].y);
            acc[i].z = fmaf(xr[i].y, w1.z, acc[i].z);
            acc[i].w = fmaf(xr[i].y, w1.w, acc[i].w);
            acc[i].x = fmaf(xr[i].z, w2.x, acc[i].x);
            acc[i].y = fmaf(xr[i].z, w2.y, acc[i].y);
            acc[i].z = fmaf(xr[i].z, w2.z, acc[i].z);
            acc[i].w = fmaf(xr[i].z, w2.w, acc[i].w);
            acc[i].x = fmaf(xr[i].w, w3.x, acc[i].x);
            acc[i].y = fmaf(xr[i].w, w3.y, acc[i].y);
            acc[i].z = fmaf(xr[i].w, w3.z, acc[i].z);
            acc[i].w = fmaf(xr[i].w, w3.w, acc[i].w);
        }
    }

    #pragma unroll
    for (int i = 0; i < 8; ++i) {
        int row = row0 + g * 8 + i;
        if (row < N_NODES) ((float4*)Y)[(size_t)row * 32 + lane] = acc[i];
    }
}

// ---------- gather-aggregate: one wave per node, 2 edges per load ----------
// At the XCD<->LLC fabric floor (~188MB compulsory fetch @ ~400GB/s/XCD).
__global__ __launch_bounds__(256) void k_gather3(const float* __restrict__ t,
                                                 const int2* __restrict__ csr_uw,
                                                 const int* __restrict__ row_start,
                                                 const int* __restrict__ cnt,
                                                 const float* __restrict__ dinv,
                                                 const float* __restrict__ b,
                                                 float* __restrict__ h) {
    const int wid = threadIdx.x >> 6;
    const int lane = threadIdx.x & 63;
    const int half = lane >> 5;
    const int sub = lane & 31;
    const int v = blockIdx.x * 4 + wid;

    const int start = row_start[v];
    const int len = cnt[v];
    const float dv = dinv[v];
    const float4* tv = (const float4*)t;

    float4 a0 = {0,0,0,0}, a1 = {0,0,0,0};

    for (int base = 0; base < len; base += 64) {
        int m = len - base; if (m > 64) m = 64;
        int2 uw = make_int2(0, 0);
        if (lane < m) uw = csr_uw[start + base + lane];

        int j = 0;
        for (; j + 3 < m; j += 4) {
            int   u0 = __shfl(uw.x, j     + half);
            float w0 = __int_as_float(__shfl(uw.y, j     + half));
            int   u1 = __shfl(uw.x, j + 2 + half);
            float w1 = __int_as_float(__shfl(uw.y, j + 2 + half));
            float4 t0 = tv[(size_t)u0 * 32 + sub];
            float4 t1 = tv[(size_t)u1 * 32 + sub];
            a0.x = fmaf(w0, t0.x, a0.x); a0.y = fmaf(w0, t0.y, a0.y);
            a0.z = fmaf(w0, t0.z, a0.z); a0.w = fmaf(w0, t0.w, a0.w);
            a1.x = fmaf(w1, t1.x, a1.x); a1.y = fmaf(w1, t1.y, a1.y);
            a1.z = fmaf(w1, t1.z, a1.z); a1.w = fmaf(w1, t1.w, a1.w);
        }
        for (; j + 1 < m; j += 2) {
            int   u = __shfl(uw.x, j + half);
            float w = __int_as_float(__shfl(uw.y, j + half));
            float4 tt = tv[(size_t)u * 32 + sub];
            a0.x = fmaf(w, tt.x, a0.x); a0.y = fmaf(w, tt.y, a0.y);
            a0.z = fmaf(w, tt.z, a0.z); a0.w = fmaf(w, tt.w, a0.w);
        }
        if (j < m) {
            int   u = __shfl(uw.x, j);
            float w = (half == 0) ? __int_as_float(__shfl(uw.y, j)) : 0.f;
            float4 tt = tv[(size_t)u * 32 + sub];
            a0.x = fmaf(w, tt.x, a0.x); a0.y = fmaf(w, tt.y, a0.y);
            a0.z = fmaf(w, tt.z, a0.z); a0.w = fmaf(w, tt.w, a0.w);
        }
    }

    float4 s;
    s.x = a0.x + a1.x; s.y = a0.y + a1.y;
    s.z = a0.z + a1.z; s.w = a0.w + a1.w;
    s.x += __shfl_xor(s.x, 32);
    s.y += __shfl_xor(s.y, 32);
    s.z += __shfl_xor(s.z, 32);
    s.w += __shfl_xor(s.w, 32);

    if (half == 0) {
        float4 self = tv[(size_t)v * 32 + sub];
        float4 bb = ((const float4*)b)[sub];
        float4 o;
        o.x = fmaxf(fmaf(dv, fmaf(dv, self.x, s.x), bb.x), 0.f);
        o.y = fmaxf(fmaf(dv, fmaf(dv, self.y, s.y), bb.y), 0.f);
        o.z = fmaxf(fmaf(dv, fmaf(dv, self.z, s.z), bb.z), 0.f);
        o.w = fmaxf(fmaf(dv, fmaf(dv, self.w, s.w), bb.w), 0.f);
        ((float4*)h)[(size_t)v * 32 + sub] = o;
    }
}

// ---------- segmented mean pool (batch sorted) ----------
__global__ __launch_bounds__(128) void k_pool2(const float* __restrict__ h,
                                               const int* __restrict__ batch,
                                               float* __restrict__ psum) {
    const int c = threadIdx.x;
    const int v0 = blockIdx.x * POOL_CHUNK;
    __shared__ int bg[POOL_CHUNK];
    if (c < POOL_CHUNK) bg[c] = batch[v0 + c];
    __syncthreads();

    float acc = 0.f;
    int g = bg[0];
    #pragma unroll 5
    for (int j = 0; j < POOL_CHUNK; ++j) {
        int bgj = bg[j];
        float val = h[(size_t)(v0 + j) * CH + c];
        if (bgj != g) {
            atomicAdd(&psum[g * CH + c], acc);
            acc = 0.f;
            g = bgj;
        }
        acc += val;
    }
    atomicAdd(&psum[g * CH + c], acc);
}

// ---------- classifier head (per-graph count via binary search inline) ----------
__global__ __launch_bounds__(128) void k_classify(const float* __restrict__ psum,
                                                  const int* __restrict__ batch,
                                                  const float* __restrict__ Wc,
                                                  const float* __restrict__ bc,
                                                  float* __restrict__ out) {
    __shared__ float p[CH];
    __shared__ float sinv;
    int g = blockIdx.x;
    int tid = threadIdx.x;
    if (tid == 0) {
        int lo = 0, hi = N_NODES;
        while (lo < hi) { int mid = (lo + hi) >> 1; if (batch[mid] < g) lo = mid + 1; else hi = mid; }
        int start = lo;
        lo = 0; hi = N_NODES;
        while (lo < hi) { int mid = (lo + hi) >> 1; if (batch[mid] < g + 1) lo = mid + 1; else hi = mid; }
        sinv = 1.0f / fmaxf((float)(lo - start), 1.0f);
    }
    __syncthreads();
    p[tid] = psum[g * CH + tid] * sinv;
    __syncthreads();
    if (tid < NOUT) {
        float acc = bc[tid];
        #pragma unroll 4
        for (int k = 0; k < CH; ++k) acc += p[k] * Wc[k * NOUT + tid];
        out[g * NOUT + tid] = acc;
    }
}

extern "C" void kernel_launch(void* const* d_in, const int* in_sizes, int n_in,
                              void* d_out, int out_size, void* d_ws, size_t ws_size,
                              hipStream_t stream) {
    const float* x     = (const float*)d_in[0];
    const int*   ei    = (const int*)d_in[1];
    const int*   batch = (const int*)d_in[2];
    const float* W1    = (const float*)d_in[3];
    const float* b1    = (const float*)d_in[4];
    const float* W2    = (const float*)d_in[5];
    const float* b2    = (const float*)d_in[6];
    const float* Wc    = (const float*)d_in[7];
    const float* bc    = (const float*)d_in[8];
    float* out = (float*)d_out;

    const int* src = ei;
    const int* dst = ei + N_EDGES;

    float* dinv      = (float*)d_ws;                       // N
    int*   cnt       = (int*)(dinv + N_NODES);             // N
    int*   row_start = cnt + N_NODES;                      // N
    int*   fill_pos  = row_start + N_NODES;                // N
    int*   bsum      = fill_pos + N_NODES;                 // 256
    int2*  csr_uw    = (int2*)(bsum + 256);                // E int2
    float* tbuf      = (float*)(csr_uw + N_EDGES);         // N*CH
    float* hbuf      = tbuf + (size_t)N_NODES * CH;        // N*CH
    float* psum      = hbuf + (size_t)N_NODES * CH;        // G*CH

    // ---- CSR build + norm ----
    hipMemsetAsync(cnt, 0, N_NODES * sizeof(int), stream);
    k_hist<<<(N_EDGES + 255) / 256, 256, 0, stream>>>(dst, cnt);
    k_scan1<<<N_SCAN_BLOCKS, SCAN_B, 0, stream>>>(cnt, row_start, bsum);
    k_scan2<<<1, SCAN_B, 0, stream>>>(bsum);
    k_scan3<<<N_SCAN_BLOCKS, SCAN_B, 0, stream>>>(row_start, bsum, fill_pos, cnt, dinv);
    k_fill<<<(N_EDGES + 255) / 256, 256, 0, stream>>>(src, dst, fill_pos, dinv, csr_uw);

    // ---- conv1 ----
    k_gemm3<<<(N_NODES + GR - 1) / GR, 256, 0, stream>>>(x, W1, tbuf);
    k_gather3<<<N_NODES / 4, 256, 0, stream>>>(tbuf, csr_uw, row_start, cnt, dinv, b1, hbuf);

    // ---- conv2 ----
    k_gemm3<<<(N_NODES + GR - 1) / GR, 256, 0, stream>>>(hbuf, W2, tbuf);
    k_gather3<<<N_NODES / 4, 256, 0, stream>>>(tbuf, csr_uw, row_start, cnt, dinv, b2, hbuf);

    // ---- pool + head ----
    hipMemsetAsync(psum, 0, NUM_GRAPHS * CH * sizeof(float), stream);
    k_pool2<<<N_NODES / POOL_CHUNK, 128, 0, stream>>>(hbuf, batch, psum);
    k_classify<<<NUM_GRAPHS, 128, 0, stream>>>(psum, batch, Wc, bc, out);
}

// Round 7
// 378.238 us; speedup vs baseline: 1.0187x; 1.0187x over previous
//
#include <hip/hip_runtime.h>

#define N_NODES 50000
#define N_EDGES 800000
#define CH 128
#define NOUT 10
#define NUM_GRAPHS 128
#define SCAN_B 256
#define N_SCAN_BLOCKS ((N_NODES + SCAN_B - 1) / SCAN_B)   // 196
#define POOL_CHUNK 50
#define GR 64                                              // gemm rows per block
#define GEMM_BLOCKS ((N_NODES + GR - 1) / GR)              // 782
#define GEMM_HALF ((GEMM_BLOCKS + 1) / 2)                  // 391
#define EDGE_BLOCKS ((N_EDGES + 1023) / 1024)              // 782 (4 edges/thread)

// ================= GEMM body (64 rows x 128 cols, 256 thr) =================
__device__ __forceinline__ void gemm_body(const float* __restrict__ X,
                                          const float* __restrict__ W,
                                          float* __restrict__ Y,
                                          float xs[GR][CH], int gemm_bid) {
    const int tid = threadIdx.x;
    const int lane = tid & 31;
    const int g = tid >> 5;
    const int row0 = gemm_bid * GR;

    const float4* Xv = (const float4*)X;
    #pragma unroll
    for (int i = 0; i < 8; ++i) {
        int f = tid + i * 256;
        int r = f >> 5;
        float4 val = make_float4(0.f, 0.f, 0.f, 0.f);
        if (row0 + r < N_NODES) val = Xv[(size_t)row0 * 32 + f];
        ((float4*)xs)[f] = val;
    }
    __syncthreads();

    float4 acc[8];
    #pragma unroll
    for (int i = 0; i < 8; ++i) acc[i] = make_float4(0.f, 0.f, 0.f, 0.f);

    const float4* Wv = (const float4*)W;
    #pragma unroll 2
    for (int k4 = 0; k4 < CH / 4; ++k4) {
        float4 w0 = Wv[(k4 * 4 + 0) * 32 + lane];
        float4 w1 = Wv[(k4 * 4 + 1) * 32 + lane];
        float4 w2 = Wv[(k4 * 4 + 2) * 32 + lane];
        float4 w3 = Wv[(k4 * 4 + 3) * 32 + lane];
        float4 xr[8];
        #pragma unroll
        for (int i = 0; i < 8; ++i)
            xr[i] = *(const float4*)&xs[g * 8 + i][k4 * 4];
        #pragma unroll
        for (int i = 0; i < 8; ++i) {
            acc[i].x = fmaf(xr[i].x, w0.x, acc[i].x);
            acc[i].y = fmaf(xr[i].x, w0.y, acc[i].y);
            acc[i].z = fmaf(xr[i].x, w0.z, acc[i].z);
            acc[i].w = fmaf(xr[i].x, w0.w, acc[i].w);
            acc[i].x = fmaf(xr[i].y, w1.x, acc[i].x);
            acc[i].y = fmaf(xr[i].y, w1.y, acc[i].y);
            acc[i].z = fmaf(xr[i].y, w1.z, acc[i].z);
            acc[i].w = fmaf(xr[i].y, w1.w, acc[i].w);
            acc[i].x = fmaf(xr[i].z, w2.x, acc[i].x);
            acc[i].y = fmaf(xr[i].z, w2.y, acc[i].y);
            acc[i].z = fmaf(xr[i].z, w2.z, acc[i].z);
            acc[i].w = fmaf(xr[i].z, w2.w, acc[i].w);
            acc[i].x = fmaf(xr[i].w, w3.x, acc[i].x);
            acc[i].y = fmaf(xr[i].w, w3.y, acc[i].y);
            acc[i].z = fmaf(xr[i].w, w3.z, acc[i].z);
            acc[i].w = fmaf(xr[i].w, w3.w, acc[i].w);
        }
    }

    #pragma unroll
    for (int i = 0; i < 8; ++i) {
        int row = row0 + g * 8 + i;
        if (row < N_NODES) ((float4*)Y)[(size_t)row * 32 + lane] = acc[i];
    }
}

// ============ K1: gemm1 first half (blocks 0..390) ∥ hist (rest) ============
__global__ __launch_bounds__(256) void k_gemm_hist(const float* __restrict__ X,
                                                   const float* __restrict__ W,
                                                   float* __restrict__ Y,
                                                   const int* __restrict__ dst,
                                                   int* __restrict__ cnt) {
    __shared__ float xs[GR][CH];
    int bid = blockIdx.x;
    if (bid < GEMM_HALF) {
        gemm_body(X, W, Y, xs, bid);
    } else {
        int base = (bid - GEMM_HALF) * 1024 + threadIdx.x;
        #pragma unroll
        for (int i = 0; i < 4; ++i) {
            int e = base + i * 256;
            if (e < N_EDGES) atomicAdd(&cnt[dst[e]], 1);
        }
    }
}

// ============ K2: gemm1 second half ∥ fill (4 edges/thread, batched) ========
__global__ __launch_bounds__(256) void k_gemm_fill(const float* __restrict__ X,
                                                   const float* __restrict__ W,
                                                   float* __restrict__ Y,
                                                   const int* __restrict__ src,
                                                   const int* __restrict__ dst,
                                                   int* __restrict__ fill_pos,
                                                   int* __restrict__ csr_src) {
    __shared__ float xs[GR][CH];
    int bid = blockIdx.x;
    if (bid < GEMM_BLOCKS - GEMM_HALF) {
        gemm_body(X, W, Y, xs, bid + GEMM_HALF);
    } else {
        int base = (bid - (GEMM_BLOCKS - GEMM_HALF)) * 1024 + threadIdx.x;
        int d[4], s[4], pos[4];
        bool ok[4];
        #pragma unroll
        for (int i = 0; i < 4; ++i) {
            int e = base + i * 256;
            ok[i] = (e < N_EDGES);
            d[i] = ok[i] ? dst[e] : 0;
            s[i] = ok[i] ? src[e] : 0;
        }
        #pragma unroll
        for (int i = 0; i < 4; ++i)
            if (ok[i]) pos[i] = atomicAdd(&fill_pos[d[i]], 1);   // 4 independent
        #pragma unroll
        for (int i = 0; i < 4; ++i)
            if (ok[i]) csr_src[pos[i]] = s[i];
    }
}

// ================= scans =================
__global__ __launch_bounds__(SCAN_B) void k_scan1(const int* __restrict__ cnt,
                                                  int* __restrict__ row_start,
                                                  int* __restrict__ bsum) {
    __shared__ int s[SCAN_B];
    int tid = threadIdx.x;
    int i = blockIdx.x * SCAN_B + tid;
    int v = (i < N_NODES) ? cnt[i] : 0;
    s[tid] = v;
    __syncthreads();
    for (int off = 1; off < SCAN_B; off <<= 1) {
        int t = (tid >= off) ? s[tid - off] : 0;
        __syncthreads();
        s[tid] += t;
        __syncthreads();
    }
    if (i < N_NODES) row_start[i] = s[tid] - v;
    if (tid == SCAN_B - 1) bsum[blockIdx.x] = s[tid];
}

__global__ __launch_bounds__(SCAN_B) void k_scan2(int* __restrict__ bsum) {
    __shared__ int s[SCAN_B];
    int tid = threadIdx.x;
    int v = (tid < N_SCAN_BLOCKS) ? bsum[tid] : 0;
    s[tid] = v;
    __syncthreads();
    for (int off = 1; off < SCAN_B; off <<= 1) {
        int t = (tid >= off) ? s[tid - off] : 0;
        __syncthreads();
        s[tid] += t;
        __syncthreads();
    }
    if (tid < N_SCAN_BLOCKS) bsum[tid] = s[tid] - v;
}

__global__ __launch_bounds__(SCAN_B) void k_scan3(int* __restrict__ row_start,
                                                  const int* __restrict__ bsum,
                                                  int* __restrict__ fill_pos,
                                                  const int* __restrict__ cnt,
                                                  float* __restrict__ dinv) {
    int i = blockIdx.x * SCAN_B + threadIdx.x;
    if (i < N_NODES) {
        int rs = row_start[i] + bsum[blockIdx.x];
        row_start[i] = rs;
        fill_pos[i] = rs;
        dinv[i] = rsqrtf((float)(cnt[i] + 1));
    }
}

// ===== gather-aggregate (R4-proven shape): one wave per node, float2 lanes ===
__global__ __launch_bounds__(256) void k_gather2(const float* __restrict__ t,
                                                 const int* __restrict__ csr_src,
                                                 const int* __restrict__ row_start,
                                                 const int* __restrict__ cnt,
                                                 const float* __restrict__ dinv,
                                                 const float* __restrict__ b,
                                                 float* __restrict__ h) {
    const int wid = threadIdx.x >> 6;
    const int lane = threadIdx.x & 63;
    const int v = blockIdx.x * 4 + wid;      // 12500 * 4 = 50000 exactly

    const int start = row_start[v];
    const int len = cnt[v];
    const float dv = dinv[v];
    const float2* tv = (const float2*)t;

    float2 a0 = {0.f, 0.f}, a1 = {0.f, 0.f}, a2 = {0.f, 0.f}, a3 = {0.f, 0.f};

    for (int base = 0; base < len; base += 64) {
        int m = len - base; if (m > 64) m = 64;
        int u_l = 0;
        if (lane < m) u_l = csr_src[start + base + lane];   // coalesced
        float w_l = dinv[u_l];                               // scattered 4B/lane
        int j = 0;
        for (; j + 3 < m; j += 4) {
            int u0 = __shfl(u_l, j),     u1 = __shfl(u_l, j + 1);
            int u2 = __shfl(u_l, j + 2), u3 = __shfl(u_l, j + 3);
            float w0 = __shfl(w_l, j),     w1 = __shfl(w_l, j + 1);
            float w2 = __shfl(w_l, j + 2), w3 = __shfl(w_l, j + 3);
            float2 t0 = tv[(size_t)u0 * 64 + lane];
            float2 t1 = tv[(size_t)u1 * 64 + lane];
            float2 t2 = tv[(size_t)u2 * 64 + lane];
            float2 t3 = tv[(size_t)u3 * 64 + lane];
            a0.x = fmaf(w0, t0.x, a0.x); a0.y = fmaf(w0, t0.y, a0.y);
            a1.x = fmaf(w1, t1.x, a1.x); a1.y = fmaf(w1, t1.y, a1.y);
            a2.x = fmaf(w2, t2.x, a2.x); a2.y = fmaf(w2, t2.y, a2.y);
            a3.x = fmaf(w3, t3.x, a3.x); a3.y = fmaf(w3, t3.y, a3.y);
        }
        for (; j < m; ++j) {
            int u = __shfl(u_l, j);
            float w = __shfl(w_l, j);
            float2 tt = tv[(size_t)u * 64 + lane];
            a0.x = fmaf(w, tt.x, a0.x); a0.y = fmaf(w, tt.y, a0.y);
        }
    }

    float2 self = tv[(size_t)v * 64 + lane];
    float sx = a0.x + a1.x + a2.x + a3.x + dv * self.x;
    float sy = a0.y + a1.y + a2.y + a3.y + dv * self.y;
    float2 bb = ((const float2*)b)[lane];
    float2 o;
    o.x = fmaxf(fmaf(dv, sx, bb.x), 0.f);
    o.y = fmaxf(fmaf(dv, sy, bb.y), 0.f);
    ((float2*)h)[(size_t)v * 64 + lane] = o;
}

// ================= plain GEMM (conv2) =================
__global__ __launch_bounds__(256) void k_gemm3(const float* __restrict__ X,
                                               const float* __restrict__ W,
                                               float* __restrict__ Y) {
    __shared__ float xs[GR][CH];
    gemm_body(X, W, Y, xs, blockIdx.x);
}

// ================= segmented mean pool (batch sorted) =================
__global__ __launch_bounds__(128) void k_pool2(const float* __restrict__ h,
                                               const int* __restrict__ batch,
                                               float* __restrict__ psum) {
    const int c = threadIdx.x;
    const int v0 = blockIdx.x * POOL_CHUNK;
    __shared__ int bg[POOL_CHUNK];
    if (c < POOL_CHUNK) bg[c] = batch[v0 + c];
    __syncthreads();

    float acc = 0.f;
    int g = bg[0];
    #pragma unroll 5
    for (int j = 0; j < POOL_CHUNK; ++j) {
        int bgj = bg[j];
        float val = h[(size_t)(v0 + j) * CH + c];
        if (bgj != g) {
            atomicAdd(&psum[g * CH + c], acc);
            acc = 0.f;
            g = bgj;
        }
        acc += val;
    }
    atomicAdd(&psum[g * CH + c], acc);
}

// ================= classifier head (count via binary search) =================
__global__ __launch_bounds__(128) void k_classify(const float* __restrict__ psum,
                                                  const int* __restrict__ batch,
                                                  const float* __restrict__ Wc,
                                                  const float* __restrict__ bc,
                                                  float* __restrict__ out) {
    __shared__ float p[CH];
    __shared__ float sinv;
    int g = blockIdx.x;
    int tid = threadIdx.x;
    if (tid == 0) {
        int lo = 0, hi = N_NODES;
        while (lo < hi) { int mid = (lo + hi) >> 1; if (batch[mid] < g) lo = mid + 1; else hi = mid; }
        int start = lo;
        lo = 0; hi = N_NODES;
        while (lo < hi) { int mid = (lo + hi) >> 1; if (batch[mid] < g + 1) lo = mid + 1; else hi = mid; }
        sinv = 1.0f / fmaxf((float)(lo - start), 1.0f);
    }
    __syncthreads();
    p[tid] = psum[g * CH + tid] * sinv;
    __syncthreads();
    if (tid < NOUT) {
        float acc = bc[tid];
        #pragma unroll 4
        for (int k = 0; k < CH; ++k) acc += p[k] * Wc[k * NOUT + tid];
        out[g * NOUT + tid] = acc;
    }
}

extern "C" void kernel_launch(void* const* d_in, const int* in_sizes, int n_in,
                              void* d_out, int out_size, void* d_ws, size_t ws_size,
                              hipStream_t stream) {
    const float* x     = (const float*)d_in[0];
    const int*   ei    = (const int*)d_in[1];
    const int*   batch = (const int*)d_in[2];
    const float* W1    = (const float*)d_in[3];
    const float* b1    = (const float*)d_in[4];
    const float* W2    = (const float*)d_in[5];
    const float* b2    = (const float*)d_in[6];
    const float* Wc    = (const float*)d_in[7];
    const float* bc    = (const float*)d_in[8];
    float* out = (float*)d_out;

    const int* src = ei;
    const int* dst = ei + N_EDGES;

    float* dinv      = (float*)d_ws;                       // N
    int*   cnt       = (int*)(dinv + N_NODES);             // N
    int*   row_start = cnt + N_NODES;                      // N
    int*   fill_pos  = row_start + N_NODES;                // N
    int*   bsum      = fill_pos + N_NODES;                 // 256
    int*   csr_src   = bsum + 256;                         // E
    float* tbuf      = (float*)(csr_src + N_EDGES);        // N*CH
    float* hbuf      = tbuf + (size_t)N_NODES * CH;        // N*CH
    float* psum      = hbuf + (size_t)N_NODES * CH;        // G*CH

    // ---- CSR build overlapped with conv1's GEMM ----
    hipMemsetAsync(cnt, 0, N_NODES * sizeof(int), stream);
    k_gemm_hist<<<GEMM_HALF + EDGE_BLOCKS, 256, 0, stream>>>(x, W1, tbuf, dst, cnt);
    k_scan1<<<N_SCAN_BLOCKS, SCAN_B, 0, stream>>>(cnt, row_start, bsum);
    k_scan2<<<1, SCAN_B, 0, stream>>>(bsum);
    k_scan3<<<N_SCAN_BLOCKS, SCAN_B, 0, stream>>>(row_start, bsum, fill_pos, cnt, dinv);
    k_gemm_fill<<<(GEMM_BLOCKS - GEMM_HALF) + EDGE_BLOCKS, 256, 0, stream>>>(
        x, W1, tbuf, src, dst, fill_pos, csr_src);

    // ---- conv1 aggregate ----
    k_gather2<<<N_NODES / 4, 256, 0, stream>>>(tbuf, csr_src, row_start, cnt, dinv, b1, hbuf);

    // ---- conv2 ----
    k_gemm3<<<GEMM_BLOCKS, 256, 0, stream>>>(hbuf, W2, tbuf);
    k_gather2<<<N_NODES / 4, 256, 0, stream>>>(tbuf, csr_src, row_start, cnt, dinv, b2, hbuf);

    // ---- pool + head ----
    hipMemsetAsync(psum, 0, NUM_GRAPHS * CH * sizeof(float), stream);
    k_pool2<<<N_NODES / POOL_CHUNK, 128, 0, stream>>>(hbuf, batch, psum);
    k_classify<<<NUM_GRAPHS, 128, 0, stream>>>(psum, batch, Wc, bc, out);
}

// Round 8
// 366.411 us; speedup vs baseline: 1.0516x; 1.0323x over previous
//
#include <hip/hip_runtime.h>

#define N_NODES 50000
#define N_EDGES 800000
#define CH 128
#define NOUT 10
#define NUM_GRAPHS 128
#define SCAN_B 256
#define N_SCAN_BLOCKS ((N_NODES + SCAN_B - 1) / SCAN_B)   // 196
#define POOL_CHUNK 50
#define GR 64                                              // gemm rows per block
#define GEMM_BLOCKS ((N_NODES + GR - 1) / GR)              // 782
#define FILL_SEGS 128
#define FILL_CHUNK (N_EDGES / FILL_SEGS)                   // 6250
#define DST_RANGE (N_NODES / 8)                            // 6250

// ================= GEMM body: 64 rows x 128 cols, 256 thr, W prefetch ========
__device__ __forceinline__ void gemm_body(const float* __restrict__ X,
                                          const float* __restrict__ W,
                                          float* __restrict__ Y,
                                          float xs[GR][CH], int bid) {
    const int tid = threadIdx.x;
    const int lane = tid & 31;
    const int g = tid >> 5;
    const int row0 = bid * GR;

    const float4* Xv = (const float4*)X;
    #pragma unroll
    for (int i = 0; i < 8; ++i) {
        int f = tid + i * 256;
        int r = f >> 5;
        float4 val = make_float4(0.f, 0.f, 0.f, 0.f);
        if (row0 + r < N_NODES) val = Xv[(size_t)row0 * 32 + f];
        ((float4*)xs)[f] = val;
    }
    __syncthreads();

    float4 acc[8];
    #pragma unroll
    for (int i = 0; i < 8; ++i) acc[i] = make_float4(0.f, 0.f, 0.f, 0.f);

    const float4* Wv = (const float4*)W;
    float4 w0 = Wv[0 * 32 + lane];
    float4 w1 = Wv[1 * 32 + lane];
    float4 w2 = Wv[2 * 32 + lane];
    float4 w3 = Wv[3 * 32 + lane];

    #pragma unroll 2
    for (int k4 = 0; k4 < CH / 4; ++k4) {
        const int nk = (k4 + 1) & (CH / 4 - 1);       // wrap: last prefetch harmless
        float4 n0 = Wv[(nk * 4 + 0) * 32 + lane];     // prefetch next chunk's W
        float4 n1 = Wv[(nk * 4 + 1) * 32 + lane];
        float4 n2 = Wv[(nk * 4 + 2) * 32 + lane];
        float4 n3 = Wv[(nk * 4 + 3) * 32 + lane];
        float4 xr[8];
        #pragma unroll
        for (int i = 0; i < 8; ++i)
            xr[i] = *(const float4*)&xs[g * 8 + i][k4 * 4];
        #pragma unroll
        for (int i = 0; i < 8; ++i) {
            acc[i].x = fmaf(xr[i].x, w0.x, acc[i].x);
            acc[i].y = fmaf(xr[i].x, w0.y, acc[i].y);
            acc[i].z = fmaf(xr[i].x, w0.z, acc[i].z);
            acc[i].w = fmaf(xr[i].x, w0.w, acc[i].w);
            acc[i].x = fmaf(xr[i].y, w1.x, acc[i].x);
            acc[i].y = fmaf(xr[i].y, w1.y, acc[i].y);
            acc[i].z = fmaf(xr[i].y, w1.z, acc[i].z);
            acc[i].w = fmaf(xr[i].y, w1.w, acc[i].w);
            acc[i].x = fmaf(xr[i].z, w2.x, acc[i].x);
            acc[i].y = fmaf(xr[i].z, w2.y, acc[i].y);
            acc[i].z = fmaf(xr[i].z, w2.z, acc[i].z);
            acc[i].w = fmaf(xr[i].z, w2.w, acc[i].w);
            acc[i].x = fmaf(xr[i].w, w3.x, acc[i].x);
            acc[i].y = fmaf(xr[i].w, w3.y, acc[i].y);
            acc[i].z = fmaf(xr[i].w, w3.z, acc[i].z);
            acc[i].w = fmaf(xr[i].w, w3.w, acc[i].w);
        }
        w0 = n0; w1 = n1; w2 = n2; w3 = n3;
    }

    #pragma unroll
    for (int i = 0; i < 8; ++i) {
        int row = row0 + g * 8 + i;
        if (row < N_NODES) ((float4*)Y)[(size_t)row * 32 + lane] = acc[i];
    }
}

// conv1 GEMM; blocks 0..195 also zero cnt (before hist kernel runs)
__global__ __launch_bounds__(256, 3) void k_gemm4(const float* __restrict__ X,
                                                  const float* __restrict__ W,
                                                  float* __restrict__ Y,
                                                  int* __restrict__ cnt) {
    if (blockIdx.x < N_SCAN_BLOCKS) {
        int idx = blockIdx.x * 256 + threadIdx.x;
        if (idx < N_NODES) cnt[idx] = 0;
    }
    __shared__ float xs[GR][CH];
    gemm_body(X, W, Y, xs, blockIdx.x);
}

// conv2 GEMM; blocks 0..63 also zero psum (before pool kernel runs)
__global__ __launch_bounds__(256, 3) void k_gemm4b(const float* __restrict__ X,
                                                   const float* __restrict__ W,
                                                   float* __restrict__ Y,
                                                   float* __restrict__ psum) {
    if (blockIdx.x < 64) {
        psum[blockIdx.x * 256 + threadIdx.x] = 0.f;
    }
    __shared__ float xs[GR][CH];
    gemm_body(X, W, Y, xs, blockIdx.x);
}

// ============ XCD-partitioned hist: block b handles dst range (b&7) =========
__global__ __launch_bounds__(256) void k_hist_x(const int* __restrict__ dst,
                                                int* __restrict__ cnt) {
    const int xcd = blockIdx.x & 7;
    const int seg = blockIdx.x >> 3;
    const int lo = xcd * DST_RANGE, hi = lo + DST_RANGE;
    const int base = seg * FILL_CHUNK;
    for (int it = 0; it < FILL_CHUNK; it += 256) {
        int e = base + it + threadIdx.x;
        if (it + (int)threadIdx.x < FILL_CHUNK) {
            int d = dst[e];
            if (d >= lo && d < hi) atomicAdd(&cnt[d], 1);
        }
    }
}

// ================= scans =================
__global__ __launch_bounds__(SCAN_B) void k_scan1(const int* __restrict__ cnt,
                                                  int* __restrict__ row_start,
                                                  int* __restrict__ bsum) {
    __shared__ int s[SCAN_B];
    int tid = threadIdx.x;
    int i = blockIdx.x * SCAN_B + tid;
    int v = (i < N_NODES) ? cnt[i] : 0;
    s[tid] = v;
    __syncthreads();
    for (int off = 1; off < SCAN_B; off <<= 1) {
        int t = (tid >= off) ? s[tid - off] : 0;
        __syncthreads();
        s[tid] += t;
        __syncthreads();
    }
    if (i < N_NODES) row_start[i] = s[tid] - v;
    if (tid == SCAN_B - 1) bsum[blockIdx.x] = s[tid];
}

__global__ __launch_bounds__(SCAN_B) void k_scan2(int* __restrict__ bsum) {
    __shared__ int s[SCAN_B];
    int tid = threadIdx.x;
    int v = (tid < N_SCAN_BLOCKS) ? bsum[tid] : 0;
    s[tid] = v;
    __syncthreads();
    for (int off = 1; off < SCAN_B; off <<= 1) {
        int t = (tid >= off) ? s[tid - off] : 0;
        __syncthreads();
        s[tid] += t;
        __syncthreads();
    }
    if (tid < N_SCAN_BLOCKS) bsum[tid] = s[tid] - v;
}

__global__ __launch_bounds__(SCAN_B) void k_scan3(int* __restrict__ row_start,
                                                  const int* __restrict__ bsum,
                                                  int* __restrict__ fill_pos,
                                                  const int* __restrict__ cnt,
                                                  float* __restrict__ dinv) {
    int i = blockIdx.x * SCAN_B + threadIdx.x;
    if (i < N_NODES) {
        int rs = row_start[i] + bsum[blockIdx.x];
        row_start[i] = rs;
        fill_pos[i] = rs;
        dinv[i] = rsqrtf((float)(cnt[i] + 1));
    }
}

// ============ XCD-partitioned fill ============
__global__ __launch_bounds__(256) void k_fill_x(const int* __restrict__ src,
                                                const int* __restrict__ dst,
                                                int* __restrict__ fill_pos,
                                                int* __restrict__ csr_src) {
    const int xcd = blockIdx.x & 7;
    const int seg = blockIdx.x >> 3;
    const int lo = xcd * DST_RANGE, hi = lo + DST_RANGE;
    const int base = seg * FILL_CHUNK;
    for (int it = 0; it < FILL_CHUNK; it += 256) {
        int e = base + it + threadIdx.x;
        if (it + (int)threadIdx.x < FILL_CHUNK) {
            int d = dst[e];
            if (d >= lo && d < hi) {
                int s = src[e];
                int pos = atomicAdd(&fill_pos[d], 1);
                csr_src[pos] = s;
            }
        }
    }
}

// ===== gather-aggregate (proven): one wave per node, float2 lanes ===========
__global__ __launch_bounds__(256) void k_gather2(const float* __restrict__ t,
                                                 const int* __restrict__ csr_src,
                                                 const int* __restrict__ row_start,
                                                 const int* __restrict__ cnt,
                                                 const float* __restrict__ dinv,
                                                 const float* __restrict__ b,
                                                 float* __restrict__ h) {
    const int wid = threadIdx.x >> 6;
    const int lane = threadIdx.x & 63;
    const int v = blockIdx.x * 4 + wid;      // 12500 * 4 = 50000 exactly

    const int start = row_start[v];
    const int len = cnt[v];
    const float dv = dinv[v];
    const float2* tv = (const float2*)t;

    float2 a0 = {0.f, 0.f}, a1 = {0.f, 0.f}, a2 = {0.f, 0.f}, a3 = {0.f, 0.f};

    for (int base = 0; base < len; base += 64) {
        int m = len - base; if (m > 64) m = 64;
        int u_l = 0;
        if (lane < m) u_l = csr_src[start + base + lane];   // coalesced
        float w_l = dinv[u_l];                               // scattered 4B/lane
        int j = 0;
        for (; j + 3 < m; j += 4) {
            int u0 = __shfl(u_l, j),     u1 = __shfl(u_l, j + 1);
            int u2 = __shfl(u_l, j + 2), u3 = __shfl(u_l, j + 3);
            float w0 = __shfl(w_l, j),     w1 = __shfl(w_l, j + 1);
            float w2 = __shfl(w_l, j + 2), w3 = __shfl(w_l, j + 3);
            float2 t0 = tv[(size_t)u0 * 64 + lane];
            float2 t1 = tv[(size_t)u1 * 64 + lane];
            float2 t2 = tv[(size_t)u2 * 64 + lane];
            float2 t3 = tv[(size_t)u3 * 64 + lane];
            a0.x = fmaf(w0, t0.x, a0.x); a0.y = fmaf(w0, t0.y, a0.y);
            a1.x = fmaf(w1, t1.x, a1.x); a1.y = fmaf(w1, t1.y, a1.y);
            a2.x = fmaf(w2, t2.x, a2.x); a2.y = fmaf(w2, t2.y, a2.y);
            a3.x = fmaf(w3, t3.x, a3.x); a3.y = fmaf(w3, t3.y, a3.y);
        }
        for (; j < m; ++j) {
            int u = __shfl(u_l, j);
            float w = __shfl(w_l, j);
            float2 tt = tv[(size_t)u * 64 + lane];
            a0.x = fmaf(w, tt.x, a0.x); a0.y = fmaf(w, tt.y, a0.y);
        }
    }

    float2 self = tv[(size_t)v * 64 + lane];
    float sx = a0.x + a1.x + a2.x + a3.x + dv * self.x;
    float sy = a0.y + a1.y + a2.y + a3.y + dv * self.y;
    float2 bb = ((const float2*)b)[lane];
    float2 o;
    o.x = fmaxf(fmaf(dv, sx, bb.x), 0.f);
    o.y = fmaxf(fmaf(dv, sy, bb.y), 0.f);
    ((float2*)h)[(size_t)v * 64 + lane] = o;
}

// ================= segmented mean pool (batch sorted) =================
__global__ __launch_bounds__(128) void k_pool2(const float* __restrict__ h,
                                               const int* __restrict__ batch,
                                               float* __restrict__ psum) {
    const int c = threadIdx.x;
    const int v0 = blockIdx.x * POOL_CHUNK;
    __shared__ int bg[POOL_CHUNK];
    if (c < POOL_CHUNK) bg[c] = batch[v0 + c];
    __syncthreads();

    float acc = 0.f;
    int g = bg[0];
    #pragma unroll 5
    for (int j = 0; j < POOL_CHUNK; ++j) {
        int bgj = bg[j];
        float val = h[(size_t)(v0 + j) * CH + c];
        if (bgj != g) {
            atomicAdd(&psum[g * CH + c], acc);
            acc = 0.f;
            g = bgj;
        }
        acc += val;
    }
    atomicAdd(&psum[g * CH + c], acc);
}

// ================= classifier head (count via binary search) =================
__global__ __launch_bounds__(128) void k_classify(const float* __restrict__ psum,
                                                  const int* __restrict__ batch,
                                                  const float* __restrict__ Wc,
                                                  const float* __restrict__ bc,
                                                  float* __restrict__ out) {
    __shared__ float p[CH];
    __shared__ float sinv;
    int g = blockIdx.x;
    int tid = threadIdx.x;
    if (tid == 0) {
        int lo = 0, hi = N_NODES;
        while (lo < hi) { int mid = (lo + hi) >> 1; if (batch[mid] < g) lo = mid + 1; else hi = mid; }
        int start = lo;
        lo = 0; hi = N_NODES;
        while (lo < hi) { int mid = (lo + hi) >> 1; if (batch[mid] < g + 1) lo = mid + 1; else hi = mid; }
        sinv = 1.0f / fmaxf((float)(lo - start), 1.0f);
    }
    __syncthreads();
    p[tid] = psum[g * CH + tid] * sinv;
    __syncthreads();
    if (tid < NOUT) {
        float acc = bc[tid];
        #pragma unroll 4
        for (int k = 0; k < CH; ++k) acc += p[k] * Wc[k * NOUT + tid];
        out[g * NOUT + tid] = acc;
    }
}

extern "C" void kernel_launch(void* const* d_in, const int* in_sizes, int n_in,
                              void* d_out, int out_size, void* d_ws, size_t ws_size,
                              hipStream_t stream) {
    const float* x     = (const float*)d_in[0];
    const int*   ei    = (const int*)d_in[1];
    const int*   batch = (const int*)d_in[2];
    const float* W1    = (const float*)d_in[3];
    const float* b1    = (const float*)d_in[4];
    const float* W2    = (const float*)d_in[5];
    const float* b2    = (const float*)d_in[6];
    const float* Wc    = (const float*)d_in[7];
    const float* bc    = (const float*)d_in[8];
    float* out = (float*)d_out;

    const int* src = ei;
    const int* dst = ei + N_EDGES;

    float* dinv      = (float*)d_ws;                       // N
    int*   cnt       = (int*)(dinv + N_NODES);             // N
    int*   row_start = cnt + N_NODES;                      // N
    int*   fill_pos  = row_start + N_NODES;                // N
    int*   bsum      = fill_pos + N_NODES;                 // 256
    int*   csr_src   = bsum + 256;                         // E
    float* tbuf      = (float*)(csr_src + N_EDGES);        // N*CH
    float* hbuf      = tbuf + (size_t)N_NODES * CH;        // N*CH
    float* psum      = hbuf + (size_t)N_NODES * CH;        // G*CH

    // conv1 GEMM (also zeroes cnt for the hist that follows)
    k_gemm4<<<GEMM_BLOCKS, 256, 0, stream>>>(x, W1, tbuf, cnt);

    // CSR build (XCD-partitioned hist/fill)
    k_hist_x<<<FILL_SEGS * 8, 256, 0, stream>>>(dst, cnt);
    k_scan1<<<N_SCAN_BLOCKS, SCAN_B, 0, stream>>>(cnt, row_start, bsum);
    k_scan2<<<1, SCAN_B, 0, stream>>>(bsum);
    k_scan3<<<N_SCAN_BLOCKS, SCAN_B, 0, stream>>>(row_start, bsum, fill_pos, cnt, dinv);
    k_fill_x<<<FILL_SEGS * 8, 256, 0, stream>>>(src, dst, fill_pos, csr_src);

    // conv1 aggregate
    k_gather2<<<N_NODES / 4, 256, 0, stream>>>(tbuf, csr_src, row_start, cnt, dinv, b1, hbuf);

    // conv2 (GEMM also zeroes psum for the pool that follows)
    k_gemm4b<<<GEMM_BLOCKS, 256, 0, stream>>>(hbuf, W2, tbuf, psum);
    k_gather2<<<N_NODES / 4, 256, 0, stream>>>(tbuf, csr_src, row_start, cnt, dinv, b2, hbuf);

    // pool + head
    k_pool2<<<N_NODES / POOL_CHUNK, 128, 0, stream>>>(hbuf, batch, psum);
    k_classify<<<NUM_GRAPHS, 128, 0, stream>>>(psum, batch, Wc, bc, out);
}

// Round 9
// 326.848 us; speedup vs baseline: 1.1789x; 1.1210x over previous
//
#include <hip/hip_runtime.h>

#define N_NODES 50000
#define N_EDGES 800000
#define CH 128
#define NOUT 10
#define NUM_GRAPHS 128
#define SCAN_B 256
#define N_SCAN_BLOCKS ((N_NODES + SCAN_B - 1) / SCAN_B)   // 196
#define POOL_CHUNK 50
#define GR 64                                              // gemm rows per block
#define GEMM_BLOCKS ((N_NODES + GR - 1) / GR)              // 782
#define FILL_SEGS 128
#define FILL_CHUNK (N_EDGES / FILL_SEGS)                   // 6250
#define DST_RANGE (N_NODES / 8)                            // 6250

// pack two fp32 -> bf16x2 dword, round-to-nearest-even
__device__ __forceinline__ unsigned pack_bf16(float a, float b) {
    unsigned ua = __float_as_uint(a), ub = __float_as_uint(b);
    ua += 0x7fffu + ((ua >> 16) & 1u);
    ub += 0x7fffu + ((ub >> 16) & 1u);
    return (ua >> 16) | (ub & 0xffff0000u);
}

// ============ GEMM body: Y'bf16[row] = dinv[row] * (X[row] @ W) ============
// 64 rows x 128 cols per block; 256 thr = 8 groups x 32 lanes; W prefetch.
__device__ __forceinline__ void gemm_body_bf(const float* __restrict__ X,
                                             const float* __restrict__ W,
                                             unsigned* __restrict__ Yb,
                                             const float* __restrict__ dinv,
                                             float xs[GR][CH], int bid) {
    const int tid = threadIdx.x;
    const int lane = tid & 31;
    const int g = tid >> 5;
    const int row0 = bid * GR;

    const float4* Xv = (const float4*)X;
    #pragma unroll
    for (int i = 0; i < 8; ++i) {
        int f = tid + i * 256;
        int r = f >> 5;
        float4 val = make_float4(0.f, 0.f, 0.f, 0.f);
        if (row0 + r < N_NODES) val = Xv[(size_t)row0 * 32 + f];
        ((float4*)xs)[f] = val;
    }
    __syncthreads();

    float4 acc[8];
    #pragma unroll
    for (int i = 0; i < 8; ++i) acc[i] = make_float4(0.f, 0.f, 0.f, 0.f);

    const float4* Wv = (const float4*)W;
    float4 w0 = Wv[0 * 32 + lane];
    float4 w1 = Wv[1 * 32 + lane];
    float4 w2 = Wv[2 * 32 + lane];
    float4 w3 = Wv[3 * 32 + lane];

    #pragma unroll 2
    for (int k4 = 0; k4 < CH / 4; ++k4) {
        const int nk = (k4 + 1) & (CH / 4 - 1);
        float4 n0 = Wv[(nk * 4 + 0) * 32 + lane];
        float4 n1 = Wv[(nk * 4 + 1) * 32 + lane];
        float4 n2 = Wv[(nk * 4 + 2) * 32 + lane];
        float4 n3 = Wv[(nk * 4 + 3) * 32 + lane];
        float4 xr[8];
        #pragma unroll
        for (int i = 0; i < 8; ++i)
            xr[i] = *(const float4*)&xs[g * 8 + i][k4 * 4];
        #pragma unroll
        for (int i = 0; i < 8; ++i) {
            acc[i].x = fmaf(xr[i].x, w0.x, acc[i].x);
            acc[i].y = fmaf(xr[i].x, w0.y, acc[i].y);
            acc[i].z = fmaf(xr[i].x, w0.z, acc[i].z);
            acc[i].w = fmaf(xr[i].x, w0.w, acc[i].w);
            acc[i].x = fmaf(xr[i].y, w1.x, acc[i].x);
            acc[i].y = fmaf(xr[i].y, w1.y, acc[i].y);
            acc[i].z = fmaf(xr[i].y, w1.z, acc[i].z);
            acc[i].w = fmaf(xr[i].y, w1.w, acc[i].w);
            acc[i].x = fmaf(xr[i].z, w2.x, acc[i].x);
            acc[i].y = fmaf(xr[i].z, w2.y, acc[i].y);
            acc[i].z = fmaf(xr[i].z, w2.z, acc[i].z);
            acc[i].w = fmaf(xr[i].z, w2.w, acc[i].w);
            acc[i].x = fmaf(xr[i].w, w3.x, acc[i].x);
            acc[i].y = fmaf(xr[i].w, w3.y, acc[i].y);
            acc[i].z = fmaf(xr[i].w, w3.z, acc[i].z);
            acc[i].w = fmaf(xr[i].w, w3.w, acc[i].w);
        }
        w0 = n0; w1 = n1; w2 = n2; w3 = n3;
    }

    #pragma unroll
    for (int i = 0; i < 8; ++i) {
        int row = row0 + g * 8 + i;
        if (row < N_NODES) {
            float dv = dinv[row];          // same addr across 32 lanes: broadcast
            unsigned p0 = pack_bf16(acc[i].x * dv, acc[i].y * dv);
            unsigned p1 = pack_bf16(acc[i].z * dv, acc[i].w * dv);
            ((uint2*)Yb)[(size_t)row * 32 + lane] = make_uint2(p0, p1);
        }
    }
}

__global__ __launch_bounds__(256, 3) void k_gemm5(const float* __restrict__ X,
                                                  const float* __restrict__ W,
                                                  unsigned* __restrict__ Yb,
                                                  const float* __restrict__ dinv) {
    __shared__ float xs[GR][CH];
    gemm_body_bf(X, W, Yb, dinv, xs, blockIdx.x);
}

// conv2 GEMM also zeroes psum (pool runs after)
__global__ __launch_bounds__(256, 3) void k_gemm5b(const float* __restrict__ X,
                                                   const float* __restrict__ W,
                                                   unsigned* __restrict__ Yb,
                                                   const float* __restrict__ dinv,
                                                   float* __restrict__ psum) {
    if (blockIdx.x < 64) psum[blockIdx.x * 256 + threadIdx.x] = 0.f;
    __shared__ float xs[GR][CH];
    gemm_body_bf(X, W, Yb, dinv, xs, blockIdx.x);
}

// ============ XCD-partitioned hist ============
__global__ __launch_bounds__(256) void k_hist_x(const int* __restrict__ dst,
                                                int* __restrict__ cnt) {
    const int xcd = blockIdx.x & 7;
    const int seg = blockIdx.x >> 3;
    const int lo = xcd * DST_RANGE, hi = lo + DST_RANGE;
    const int base = seg * FILL_CHUNK;
    for (int it = 0; it < FILL_CHUNK; it += 256) {
        int e = base + it + threadIdx.x;
        if (it + (int)threadIdx.x < FILL_CHUNK) {
            int d = dst[e];
            if (d >= lo && d < hi) atomicAdd(&cnt[d], 1);
        }
    }
}

// ================= scans =================
__global__ __launch_bounds__(SCAN_B) void k_scan1(const int* __restrict__ cnt,
                                                  int* __restrict__ row_start,
                                                  int* __restrict__ bsum) {
    __shared__ int s[SCAN_B];
    int tid = threadIdx.x;
    int i = blockIdx.x * SCAN_B + tid;
    int v = (i < N_NODES) ? cnt[i] : 0;
    s[tid] = v;
    __syncthreads();
    for (int off = 1; off < SCAN_B; off <<= 1) {
        int t = (tid >= off) ? s[tid - off] : 0;
        __syncthreads();
        s[tid] += t;
        __syncthreads();
    }
    if (i < N_NODES) row_start[i] = s[tid] - v;
    if (tid == SCAN_B - 1) bsum[blockIdx.x] = s[tid];
}

__global__ __launch_bounds__(SCAN_B) void k_scan2(int* __restrict__ bsum) {
    __shared__ int s[SCAN_B];
    int tid = threadIdx.x;
    int v = (tid < N_SCAN_BLOCKS) ? bsum[tid] : 0;
    s[tid] = v;
    __syncthreads();
    for (int off = 1; off < SCAN_B; off <<= 1) {
        int t = (tid >= off) ? s[tid - off] : 0;
        __syncthreads();
        s[tid] += t;
        __syncthreads();
    }
    if (tid < N_SCAN_BLOCKS) bsum[tid] = s[tid] - v;
}

__global__ __launch_bounds__(SCAN_B) void k_scan3(int* __restrict__ row_start,
                                                  const int* __restrict__ bsum,
                                                  int* __restrict__ fill_pos,
                                                  const int* __restrict__ cnt,
                                                  float* __restrict__ dinv) {
    int i = blockIdx.x * SCAN_B + threadIdx.x;
    if (i < N_NODES) {
        int rs = row_start[i] + bsum[blockIdx.x];
        row_start[i] = rs;
        fill_pos[i] = rs;
        dinv[i] = rsqrtf((float)(cnt[i] + 1));
    }
}

// ============ XCD-partitioned fill ============
__global__ __launch_bounds__(256) void k_fill_x(const int* __restrict__ src,
                                                const int* __restrict__ dst,
                                                int* __restrict__ fill_pos,
                                                int* __restrict__ csr_src) {
    const int xcd = blockIdx.x & 7;
    const int seg = blockIdx.x >> 3;
    const int lo = xcd * DST_RANGE, hi = lo + DST_RANGE;
    const int base = seg * FILL_CHUNK;
    for (int it = 0; it < FILL_CHUNK; it += 256) {
        int e = base + it + threadIdx.x;
        if (it + (int)threadIdx.x < FILL_CHUNK) {
            int d = dst[e];
            if (d >= lo && d < hi) {
                int s = src[e];
                int pos = atomicAdd(&fill_pos[d], 1);
                csr_src[pos] = s;
            }
        }
    }
}

// ===== gather over bf16 t' rows: h[v] = relu(dv*(sum t'[u] + t'[v]) + b) ====
// one wave per node; row = 64 dwords (bf16x2); lane covers ch 2L,2L+1.
__global__ __launch_bounds__(256) void k_gather_bf(const unsigned* __restrict__ tb,
                                                   const int* __restrict__ csr_src,
                                                   const int* __restrict__ row_start,
                                                   const int* __restrict__ cnt,
                                                   const float* __restrict__ dinv,
                                                   const float* __restrict__ b,
                                                   float* __restrict__ h) {
    const int wid = threadIdx.x >> 6;
    const int lane = threadIdx.x & 63;
    const int v = blockIdx.x * 4 + wid;      // 12500 * 4 = 50000 exactly

    const int start = row_start[v];
    const int len = cnt[v];
    const float dv = dinv[v];

    float x0 = 0.f, y0 = 0.f, x1 = 0.f, y1 = 0.f;
    float x2 = 0.f, y2 = 0.f, x3 = 0.f, y3 = 0.f;

    for (int base = 0; base < len; base += 64) {
        int m = len - base; if (m > 64) m = 64;
        int u_l = 0;
        if (lane < m) u_l = csr_src[start + base + lane];   // coalesced
        int j = 0;
        for (; j + 3 < m; j += 4) {
            int u0 = __shfl(u_l, j),     u1 = __shfl(u_l, j + 1);
            int u2 = __shfl(u_l, j + 2), u3 = __shfl(u_l, j + 3);
            unsigned r0 = tb[(size_t)u0 * 64 + lane];   // 256B/row coalesced
            unsigned r1 = tb[(size_t)u1 * 64 + lane];
            unsigned r2 = tb[(size_t)u2 * 64 + lane];
            unsigned r3 = tb[(size_t)u3 * 64 + lane];
            x0 += __uint_as_float(r0 << 16); y0 += __uint_as_float(r0 & 0xffff0000u);
            x1 += __uint_as_float(r1 << 16); y1 += __uint_as_float(r1 & 0xffff0000u);
            x2 += __uint_as_float(r2 << 16); y2 += __uint_as_float(r2 & 0xffff0000u);
            x3 += __uint_as_float(r3 << 16); y3 += __uint_as_float(r3 & 0xffff0000u);
        }
        for (; j < m; ++j) {
            int u = __shfl(u_l, j);
            unsigned r = tb[(size_t)u * 64 + lane];
            x0 += __uint_as_float(r << 16); y0 += __uint_as_float(r & 0xffff0000u);
        }
    }

    unsigned rs = tb[(size_t)v * 64 + lane];   // self term t'[v]
    float sx = x0 + x1 + x2 + x3 + __uint_as_float(rs << 16);
    float sy = y0 + y1 + y2 + y3 + __uint_as_float(rs & 0xffff0000u);
    float2 bb = ((const float2*)b)[lane];
    float2 o;
    o.x = fmaxf(fmaf(dv, sx, bb.x), 0.f);
    o.y = fmaxf(fmaf(dv, sy, bb.y), 0.f);
    ((float2*)h)[(size_t)v * 64 + lane] = o;
}

// ================= segmented mean pool (batch sorted) =================
__global__ __launch_bounds__(128) void k_pool2(const float* __restrict__ h,
                                               const int* __restrict__ batch,
                                               float* __restrict__ psum) {
    const int c = threadIdx.x;
    const int v0 = blockIdx.x * POOL_CHUNK;
    __shared__ int bg[POOL_CHUNK];
    if (c < POOL_CHUNK) bg[c] = batch[v0 + c];
    __syncthreads();

    float acc = 0.f;
    int g = bg[0];
    #pragma unroll 5
    for (int j = 0; j < POOL_CHUNK; ++j) {
        int bgj = bg[j];
        float val = h[(size_t)(v0 + j) * CH + c];
        if (bgj != g) {
            atomicAdd(&psum[g * CH + c], acc);
            acc = 0.f;
            g = bgj;
        }
        acc += val;
    }
    atomicAdd(&psum[g * CH + c], acc);
}

// ================= classifier head (count via binary search) =================
__global__ __launch_bounds__(128) void k_classify(const float* __restrict__ psum,
                                                  const int* __restrict__ batch,
                                                  const float* __restrict__ Wc,
                                                  const float* __restrict__ bc,
                                                  float* __restrict__ out) {
    __shared__ float p[CH];
    __shared__ float sinv;
    int g = blockIdx.x;
    int tid = threadIdx.x;
    if (tid == 0) {
        int lo = 0, hi = N_NODES;
        while (lo < hi) { int mid = (lo + hi) >> 1; if (batch[mid] < g) lo = mid + 1; else hi = mid; }
        int start = lo;
        lo = 0; hi = N_NODES;
        while (lo < hi) { int mid = (lo + hi) >> 1; if (batch[mid] < g + 1) lo = mid + 1; else hi = mid; }
        sinv = 1.0f / fmaxf((float)(lo - start), 1.0f);
    }
    __syncthreads();
    p[tid] = psum[g * CH + tid] * sinv;
    __syncthreads();
    if (tid < NOUT) {
        float acc = bc[tid];
        #pragma unroll 4
        for (int k = 0; k < CH; ++k) acc += p[k] * Wc[k * NOUT + tid];
        out[g * NOUT + tid] = acc;
    }
}

extern "C" void kernel_launch(void* const* d_in, const int* in_sizes, int n_in,
                              void* d_out, int out_size, void* d_ws, size_t ws_size,
                              hipStream_t stream) {
    const float* x     = (const float*)d_in[0];
    const int*   ei    = (const int*)d_in[1];
    const int*   batch = (const int*)d_in[2];
    const float* W1    = (const float*)d_in[3];
    const float* b1    = (const float*)d_in[4];
    const float* W2    = (const float*)d_in[5];
    const float* b2    = (const float*)d_in[6];
    const float* Wc    = (const float*)d_in[7];
    const float* bc    = (const float*)d_in[8];
    float* out = (float*)d_out;

    const int* src = ei;
    const int* dst = ei + N_EDGES;

    float*    dinv      = (float*)d_ws;                    // N
    int*      cnt       = (int*)(dinv + N_NODES);          // N
    int*      row_start = cnt + N_NODES;                   // N
    int*      fill_pos  = row_start + N_NODES;             // N
    int*      bsum      = fill_pos + N_NODES;              // 256
    int*      csr_src   = bsum + 256;                      // E
    unsigned* tb        = (unsigned*)(csr_src + N_EDGES);  // N*64 dwords (bf16 t')
    float*    hbuf      = (float*)(tb + (size_t)N_NODES * 64);  // N*CH
    float*    psum      = hbuf + (size_t)N_NODES * CH;     // G*CH

    // ---- CSR build + dinv (must precede GEMM: epilogue scales by dinv) ----
    hipMemsetAsync(cnt, 0, N_NODES * sizeof(int), stream);
    k_hist_x<<<FILL_SEGS * 8, 256, 0, stream>>>(dst, cnt);
    k_scan1<<<N_SCAN_BLOCKS, SCAN_B, 0, stream>>>(cnt, row_start, bsum);
    k_scan2<<<1, SCAN_B, 0, stream>>>(bsum);
    k_scan3<<<N_SCAN_BLOCKS, SCAN_B, 0, stream>>>(row_start, bsum, fill_pos, cnt, dinv);
    k_fill_x<<<FILL_SEGS * 8, 256, 0, stream>>>(src, dst, fill_pos, csr_src);

    // ---- conv1 ----
    k_gemm5<<<GEMM_BLOCKS, 256, 0, stream>>>(x, W1, tb, dinv);
    k_gather_bf<<<N_NODES / 4, 256, 0, stream>>>(tb, csr_src, row_start, cnt, dinv, b1, hbuf);

    // ---- conv2 (GEMM also zeroes psum) ----
    k_gemm5b<<<GEMM_BLOCKS, 256, 0, stream>>>(hbuf, W2, tb, dinv, psum);
    k_gather_bf<<<N_NODES / 4, 256, 0, stream>>>(tb, csr_src, row_start, cnt, dinv, b2, hbuf);

    // ---- pool + head ----
    k_pool2<<<N_NODES / POOL_CHUNK, 128, 0, stream>>>(hbuf, batch, psum);
    k_classify<<<NUM_GRAPHS, 128, 0, stream>>>(psum, batch, Wc, bc, out);
}